// Round 8
// baseline (262.454 us; speedup 1.0000x reference)
//
#include <hip/hip_runtime.h>

// out[n][p][m] = sum_c x[n][c][p] * rm[n][c][m]
// N=16, C=64, P=65536, M=128. Memory-bound: 256MB read + 512MB write -> floor ~122us.
// v8: ZERO-LDS / ZERO-BARRIER streaming design. x loaded directly from global in
//     MFMA B-fragment layout (each (ks,i) load: 16 consecutive fp32 per 16-lane
//     group = coalesced 64B segments; 4 waves/block share the data via L1).
//     rm A-fragments loaded once directly from global. Every wave streams
//     independently: load16 -> pack bf16 -> 4 MFMA -> 2 stores, 1-deep pipeline.
//     Rationale: v4's 161.6us is robust to all phase tweaks (v3/v5/v6/v7 all
//     regressed); the barrier'd stage/compute lockstep itself is the suspect.

#define NB   16
#define CDIM 64
#define PDIM 65536
#define MDIM 128
#define BLOCKS_PER_N 64
#define P_PER_BLOCK (PDIM / BLOCKS_PER_N)   // 1024
#define STEPS (P_PER_BLOCK / 16)            // 64

typedef __attribute__((ext_vector_type(8))) short bf16x8;
typedef __attribute__((ext_vector_type(4))) float f32x4;

// pack two fp32 -> two bf16 (RNE) in one u32
__device__ __forceinline__ unsigned int pack2bf(float flo, float fhi) {
  union { float f; unsigned int u; } a, b;
  a.f = flo; b.f = fhi;
  unsigned int ua = a.u + (0x7fffu + ((a.u >> 16) & 1u));
  unsigned int ub = b.u + (0x7fffu + ((b.u >> 16) & 1u));
  return (ua >> 16) | (ub & 0xffff0000u);
}

union pk8 { bf16x8 f; unsigned int u[4]; };

__global__ __launch_bounds__(256, 4) void nlsa_kernel(
    const float* __restrict__ x, const float* __restrict__ rm,
    float* __restrict__ out) {
  const int t = threadIdx.x;
  const int b = blockIdx.x;
  const int n  = b >> 6;                 // 64 blocks per n
  const int pb = (b & 63) * P_PER_BLOCK; // this block's pixel range

  const float* xn   = x  + (size_t)n * CDIM * PDIM;
  const float* rmn  = rm + (size_t)n * CDIM * MDIM;
  float*       outn = out + (size_t)n * PDIM * MDIM;

  const int w_ = t >> 6;    // wave: m range [32w_, 32w_+32)
  const int l  = t & 63;
  const int lo = l & 15;
  const int g  = l >> 4;

  // ---- A fragments (rm) straight from global, once.
  // A[m][c]: m = w_*32 + mt*16 + lo, c = ks*32 + g*8 + i.
  // Per (ks,i): lanes 0-15 read 16 consecutive floats (64B segment).
  bf16x8 a[2][2];
  {
    const float* rs = rmn + (size_t)(g * 8) * MDIM + w_ * 32 + lo;
#pragma unroll
    for (int mt = 0; mt < 2; ++mt)
#pragma unroll
      for (int ks = 0; ks < 2; ++ks) {
        float v[8];
#pragma unroll
        for (int i = 0; i < 8; ++i)
          v[i] = rs[(size_t)(ks * 32 + i) * MDIM + mt * 16];
        pk8 p;
#pragma unroll
        for (int j = 0; j < 4; ++j) p.u[j] = pack2bf(v[2 * j], v[2 * j + 1]);
        a[mt][ks] = p.f;
      }
  }

  // ---- streaming loop: 16 pixels per step, no LDS, no barriers.
  // B[c][p]: p = pb + s*16 + lo, c = ks*32 + g*8 + i.
  const float* xs = xn + (size_t)(g * 8) * PDIM + pb + lo;

  float v0[8], v1[8];
#pragma unroll
  for (int i = 0; i < 8; ++i) v0[i] = xs[(size_t)i * PDIM];
#pragma unroll
  for (int i = 0; i < 8; ++i) v1[i] = xs[(size_t)(32 + i) * PDIM];

  for (int s = 0; s < STEPS; ++s) {
    // pack current step's B fragments
    pk8 p0, p1;
#pragma unroll
    for (int j = 0; j < 4; ++j) {
      p0.u[j] = pack2bf(v0[2 * j], v0[2 * j + 1]);
      p1.u[j] = pack2bf(v1[2 * j], v1[2 * j + 1]);
    }

    // issue next step's loads (fly under MFMA + stores below)
    if (s + 1 < STEPS) {
      const float* sp = xs + (s + 1) * 16;
#pragma unroll
      for (int i = 0; i < 8; ++i) v0[i] = sp[(size_t)i * PDIM];
#pragma unroll
      for (int i = 0; i < 8; ++i) v1[i] = sp[(size_t)(32 + i) * PDIM];
    }

    f32x4 acc0 = {0.f, 0.f, 0.f, 0.f};
    f32x4 acc1 = {0.f, 0.f, 0.f, 0.f};
    acc0 = __builtin_amdgcn_mfma_f32_16x16x32_bf16(a[0][0], p0.f, acc0, 0, 0, 0);
    acc0 = __builtin_amdgcn_mfma_f32_16x16x32_bf16(a[0][1], p1.f, acc0, 0, 0, 0);
    acc1 = __builtin_amdgcn_mfma_f32_16x16x32_bf16(a[1][0], p0.f, acc1, 0, 0, 0);
    acc1 = __builtin_amdgcn_mfma_f32_16x16x32_bf16(a[1][1], p1.f, acc1, 0, 0, 0);

    // D: col = lane&15 = p, rows = 4g+reg (+16 per mt) -> 16B contiguous in m
    float* dst = outn + (size_t)(pb + s * 16 + lo) * MDIM + w_ * 32 + g * 4;
    *(f32x4*)(dst)      = acc0;   // m = 32w_ + 4g + {0..3}
    *(f32x4*)(dst + 16) = acc1;   // m = 32w_ + 16 + 4g + {0..3}
  }
}

extern "C" void kernel_launch(void* const* d_in, const int* in_sizes, int n_in,
                              void* d_out, int out_size, void* d_ws, size_t ws_size,
                              hipStream_t stream) {
  const float* x  = (const float*)d_in[0];   // (N, C, H, W) fp32
  const float* rm = (const float*)d_in[1];   // (N, C, M) fp32
  float* out = (float*)d_out;                // (N, P, M) fp32
  nlsa_kernel<<<dim3(NB * BLOCKS_PER_N), dim3(256), 0, stream>>>(x, rm, out);
}

// Round 9
// 177.086 us; speedup vs baseline: 1.4821x; 1.4821x over previous
//
#include <hip/hip_runtime.h>

// out[n][p][m] = sum_c x[n][c][p] * rm[n][c][m]
// N=16, C=64, P=65536, M=128. Memory-bound: 256MB read + 512MB write -> floor ~122us.
// v9 = v4 (161.6us) with lds_rm ELIMINATED (A-frags direct from global, the
//      component v8 validated) -> LDS 33KB -> 16.5KB, grid 1024 -> 1280,
//      __launch_bounds__(256,5): targets 5 blocks/CU (20 waves) vs v4's 4.
//      Clean concurrency test: v6 showed runtime ~ 1/(blocks/CU); v5/v7's
//      attempts were confounded (spill cap / 160KB-exact LDS / XS change).

#define NB   16
#define CDIM 64
#define PDIM 65536
#define MDIM 128
#define PT   128
#define NWIN 512          // PDIM / PT
#define WSTRIDE 80        // 1280 blocks / 16 n
#define XS   132          // lds_x row stride (bf16), v4-verified banks

typedef __attribute__((ext_vector_type(8))) short bf16x8;
typedef __attribute__((ext_vector_type(4))) float f32x4;

__device__ __forceinline__ unsigned short f2bf(float f) {
  union { float f; unsigned int u; } v; v.f = f;
  unsigned int u = v.u;
  u += 0x7fffu + ((u >> 16) & 1u);  // RNE
  return (unsigned short)(u >> 16);
}

// pack two fp32 -> two bf16 (RNE) in one u32
__device__ __forceinline__ unsigned int pack2bf(float flo, float fhi) {
  union { float f; unsigned int u; } a, b;
  a.f = flo; b.f = fhi;
  unsigned int ua = a.u + (0x7fffu + ((a.u >> 16) & 1u));
  unsigned int ub = b.u + (0x7fffu + ((b.u >> 16) & 1u));
  return (ua >> 16) | (ub & 0xffff0000u);
}

union pk8 { bf16x8 f; unsigned int u[4]; };

// x tile: [c][p], p XOR-swizzled by c-group -> conflict-free (2-way) gathers.
// XOR touches only p bits 4-5, so 4-elem (8B) write chunks stay contiguous.
__device__ __forceinline__ int xswz(int c, int p) {
  return c * XS + (p ^ (((c >> 3) & 3) << 4));
}

__global__ __launch_bounds__(256, 5) void nlsa_kernel(
    const float* __restrict__ x, const float* __restrict__ rm,
    float* __restrict__ out) {
  __shared__ unsigned short lds_x[CDIM * XS];     // 16.5KB total

  const int t = threadIdx.x;
  const int b = blockIdx.x;
  const int n  = b & 15;           // constant n per block
  const int w0 = b >> 4;           // first p-window, stride WSTRIDE

  const float* xn   = x  + (size_t)n * CDIM * PDIM;
  const float* rmn  = rm + (size_t)n * CDIM * MDIM;
  float*       outn = out + (size_t)n * PDIM * MDIM;

  const int cst = t >> 5;          // 0..7
  const int pst = (t & 31) * 4;    // 0..124

  float4 r[8];
  // issue tile-0 loads first so they fly under the A-frag loads
  {
    const float* src = xn + (size_t)(w0 * PT + pst);
#pragma unroll
    for (int it = 0; it < 8; ++it)
      r[it] = *(const float4*)(src + (size_t)(cst + it * 8) * PDIM);
  }

  const int w_ = t >> 6;    // wave: m range [32w_, 32w_+32)
  const int l  = t & 63;
  const int lo = l & 15;
  const int g  = l >> 4;

  // ---- A fragments (rm) straight from global (v8-validated).
  // A[m][c]: m = w_*32 + mt*16 + lo, c = ks*32 + g*8 + i.
  bf16x8 a[2][2];
  {
    const float* rs = rmn + (size_t)(g * 8) * MDIM + w_ * 32 + lo;
#pragma unroll
    for (int mt = 0; mt < 2; ++mt)
#pragma unroll
      for (int ks = 0; ks < 2; ++ks) {
        float v[8];
#pragma unroll
        for (int i = 0; i < 8; ++i)
          v[i] = rs[(size_t)(ks * 32 + i) * MDIM + mt * 16];
        pk8 p;
#pragma unroll
        for (int j = 0; j < 4; ++j) p.u[j] = pack2bf(v[2 * j], v[2 * j + 1]);
        a[mt][ks] = p.f;
      }
  }

  for (int w = w0; w < NWIN; w += WSTRIDE) {
    // barrier1: all waves done reading lds_x for previous tile (reads consumed
    // pre-barrier) -- raw barrier, no vm/store drain.
    asm volatile("" ::: "memory");
    __builtin_amdgcn_s_barrier();
    asm volatile("" ::: "memory");

    // write staged tile into lds_x (compiler inserts counted vmcnt for r)
#pragma unroll
    for (int it = 0; it < 8; ++it) {
      ushort4 v;
      v.x = f2bf(r[it].x); v.y = f2bf(r[it].y);
      v.z = f2bf(r[it].z); v.w = f2bf(r[it].w);
      *(ushort4*)&lds_x[xswz(cst + it * 8, pst)] = v;
    }

    // prefetch next tile into r (overlaps the compute phase below)
    if (w + WSTRIDE < NWIN) {
      const float* src = xn + (size_t)((w + WSTRIDE) * PT + pst);
#pragma unroll
      for (int it = 0; it < 8; ++it)
        r[it] = *(const float4*)(src + (size_t)(cst + it * 8) * PDIM);
    }

    // barrier2: lds_x writes visible; lgkm-only wait (store queue NOT drained)
    asm volatile("s_waitcnt lgkmcnt(0)" ::: "memory");
    __builtin_amdgcn_s_barrier();
    asm volatile("" ::: "memory");

    const int p_base = w * PT;
#pragma unroll
    for (int pt_ = 0; pt_ < 8; ++pt_) {
      const int pl  = pt_ * 16 + lo;
      const int pls = pl ^ (g << 4);   // matches xswz for c-groups g and g+4
      bf16x8 b0, b1;
#pragma unroll
      for (int i = 0; i < 8; ++i) {
        b0[i] = (short)lds_x[(g * 8 + i) * XS + pls];
        b1[i] = (short)lds_x[(32 + g * 8 + i) * XS + pls];
      }
      f32x4 acc0 = {0.f, 0.f, 0.f, 0.f};
      f32x4 acc1 = {0.f, 0.f, 0.f, 0.f};
      acc0 = __builtin_amdgcn_mfma_f32_16x16x32_bf16(a[0][0], b0, acc0, 0, 0, 0);
      acc0 = __builtin_amdgcn_mfma_f32_16x16x32_bf16(a[0][1], b1, acc0, 0, 0, 0);
      acc1 = __builtin_amdgcn_mfma_f32_16x16x32_bf16(a[1][0], b0, acc1, 0, 0, 0);
      acc1 = __builtin_amdgcn_mfma_f32_16x16x32_bf16(a[1][1], b1, acc1, 0, 0, 0);

      float* dst = outn + (size_t)(p_base + pl) * MDIM + w_ * 32 + g * 4;
      *(f32x4*)(dst)      = acc0;   // m = 32w_ + 4g + {0..3}
      *(f32x4*)(dst + 16) = acc1;   // m = 32w_ + 16 + 4g + {0..3}
    }
  }
}

extern "C" void kernel_launch(void* const* d_in, const int* in_sizes, int n_in,
                              void* d_out, int out_size, void* d_ws, size_t ws_size,
                              hipStream_t stream) {
  const float* x  = (const float*)d_in[0];   // (N, C, H, W) fp32
  const float* rm = (const float*)d_in[1];   // (N, C, M) fp32
  float* out = (float*)d_out;                // (N, P, M) fp32
  nlsa_kernel<<<dim3(NB * WSTRIDE), dim3(256), 0, stream>>>(x, rm, out);
}

// Round 10
// 161.419 us; speedup vs baseline: 1.6259x; 1.0971x over previous
//
#include <hip/hip_runtime.h>

// out[n][p][m] = sum_c x[n][c][p] * rm[n][c][m]
// N=16, C=64, P=65536, M=128. Memory-bound: 256MB read + 512MB write -> floor ~122us.
// v10 = v4 (161.6us) with the x-tile LDS flipped to [p][c] (MFMA-native):
//   - staging: 8 CONSECUTIVE c per thread (map (t>>5)*8+it), float4 global loads
//     unchanged-coalesced; in-register 8cx4p transpose fused into the bf16 pack;
//     4x ds_write_b128 per thread (was 8x ds_write_b64).
//   - fragments: ONE ds_read_b128 per fragment (was 8x ds_read_u16 + inserts);
//     slot-XOR swizzle s^((p>>1)&7) -> both reads and writes at the b128
//     conflict-free floor (8 lanes per 4-bank group).
//   Rationale: v4's compute phase did 128 ds_read_u16/wave-round with ~120cy
//   latency chains inside the barrier-locked phase. Everything else = v4.

#define NB   16
#define CDIM 64
#define PDIM 65536
#define MDIM 128
#define PT   128
#define BLOCKS_PER_N 64
#define TILES_PER_BLOCK 8

typedef __attribute__((ext_vector_type(8))) short bf16x8;
typedef __attribute__((ext_vector_type(4))) float f32x4;

__device__ __forceinline__ unsigned short f2bf(float f) {
  union { float f; unsigned int u; } v; v.f = f;
  unsigned int u = v.u;
  u += 0x7fffu + ((u >> 16) & 1u);  // RNE
  return (unsigned short)(u >> 16);
}

// pack two fp32 -> two bf16 (RNE) in one u32 (lo = first)
__device__ __forceinline__ unsigned int pack2bf(float flo, float fhi) {
  union { float f; unsigned int u; } a, b;
  a.f = flo; b.f = fhi;
  unsigned int ua = a.u + (0x7fffu + ((a.u >> 16) & 1u));
  unsigned int ub = b.u + (0x7fffu + ((b.u >> 16) & 1u));
  return (ua >> 16) | (ub & 0xffff0000u);
}

// rm tile swizzle (verified v1-v4): [m][64c] bf16, 16B-slot XOR
__device__ __forceinline__ int swz(int row, int col) {
  int slot = (col >> 3) ^ (row & 7);
  return row * 64 + slot * 8 + (col & 7);
}

__global__ __launch_bounds__(256, 4) void nlsa_kernel(
    const float* __restrict__ x, const float* __restrict__ rm,
    float* __restrict__ out) {
  __shared__ unsigned short lds_rm[MDIM * CDIM];  // 16KB (v4 verbatim)
  __shared__ unsigned short lds_xT[PT * CDIM];    // [p][c] bf16, 16KB

  const int t = threadIdx.x;
  const int b = blockIdx.x;
  const int n  = b >> 6;
  const int bt = b & 63;

  const float* xn   = x  + (size_t)n * CDIM * PDIM;
  const float* rmn  = rm + (size_t)n * CDIM * MDIM;
  float*       outn = out + (size_t)n * PDIM * MDIM;

  // x staging map: thread t loads float4 at (c = C8+it, p = P4..P4+3), it=0..7.
  // Per wave-instr: 2 c-rows x 512B contiguous global. 8 consecutive c/thread.
  const int C8 = (t >> 5) * 8;     // 0,8,..,56
  const int P4 = (t & 31) * 4;     // 0..124

  float4 r[8];
  {
    const float* src = xn + (size_t)(bt * PT + P4);
#pragma unroll
    for (int it = 0; it < 8; ++it)
      r[it] = *(const float4*)(src + (size_t)(C8 + it) * PDIM);
  }

  // ---- stage rm[n] -> lds_rm[m][c] bf16 (once per block, v4 verbatim)
  {
    const int m  = t & 127;
    const int cb = (t >> 7) * 4;
#pragma unroll
    for (int it = 0; it < 8; ++it) {
      const int c0 = cb + it * 8;
      ushort4 v;
      v.x = f2bf(rmn[(c0 + 0) * MDIM + m]);
      v.y = f2bf(rmn[(c0 + 1) * MDIM + m]);
      v.z = f2bf(rmn[(c0 + 2) * MDIM + m]);
      v.w = f2bf(rmn[(c0 + 3) * MDIM + m]);
      *(ushort4*)&lds_rm[swz(m, c0)] = v;
    }
  }
  __syncthreads();

  const int w_ = t >> 6;    // wave: m range [32w_, 32w_+32)
  const int l  = t & 63;
  const int lo = l & 15;
  const int g  = l >> 4;

  // A fragments (rm) in registers for the whole kernel (v4 verbatim)
  bf16x8 a[2][2];
#pragma unroll
  for (int mt = 0; mt < 2; ++mt)
#pragma unroll
    for (int ks = 0; ks < 2; ++ks)
      a[mt][ks] = *(const bf16x8*)&lds_rm[swz(w_ * 32 + mt * 16 + lo,
                                              ks * 32 + g * 8)];

  // write one [p][c] row (16B = 8 consecutive c) with slot-XOR swizzle
#define PACKROW(dp, comp)                                                    \
  {                                                                          \
    unsigned int q0 = pack2bf(r[0].comp, r[1].comp);                         \
    unsigned int q1 = pack2bf(r[2].comp, r[3].comp);                         \
    unsigned int q2 = pack2bf(r[4].comp, r[5].comp);                         \
    unsigned int q3 = pack2bf(r[6].comp, r[7].comp);                         \
    const int p_ = P4 + dp;                                                  \
    const int slot_ = (t >> 5) ^ ((p_ >> 1) & 7);                            \
    uint4 qq; qq.x = q0; qq.y = q1; qq.z = q2; qq.w = q3;                    \
    *(uint4*)&lds_xT[p_ * 64 + slot_ * 8] = qq;                              \
  }

  for (int k = 0; k < TILES_PER_BLOCK; ++k) {
    // barrier1: all waves done reading lds_xT for tile k-1 (reads consumed
    // pre-barrier) -- raw barrier, no vm/store drain.
    asm volatile("" ::: "memory");
    __builtin_amdgcn_s_barrier();
    asm volatile("" ::: "memory");

    // transpose-pack tile k into lds_xT[p][c] (counted vmcnt for r auto)
    PACKROW(0, x)
    PACKROW(1, y)
    PACKROW(2, z)
    PACKROW(3, w)

    // prefetch tile k+1 into r (overlaps the compute phase below)
    if (k + 1 < TILES_PER_BLOCK) {
      const float* src = xn + (size_t)((bt + (k + 1) * BLOCKS_PER_N) * PT + P4);
#pragma unroll
      for (int it = 0; it < 8; ++it)
        r[it] = *(const float4*)(src + (size_t)(C8 + it) * PDIM);
    }

    // barrier2: lds writes visible; lgkm-only wait (store queue NOT drained)
    asm volatile("s_waitcnt lgkmcnt(0)" ::: "memory");
    __builtin_amdgcn_s_barrier();
    asm volatile("" ::: "memory");

    const int p_base = (bt + k * BLOCKS_PER_N) * PT;
#pragma unroll
    for (int pt_ = 0; pt_ < 8; ++pt_) {
      const int prow = pt_ * 16 + lo;
      const int sx   = (prow >> 1) & 7;
      // one b128 per fragment: c = g*8..g*8+7 (b0), 32+g*8.. (b1) at p = prow
      bf16x8 b0 = *(const bf16x8*)&lds_xT[prow * 64 + ((g ^ sx)) * 8];
      bf16x8 b1 = *(const bf16x8*)&lds_xT[prow * 64 + (((4 + g) ^ sx)) * 8];

      f32x4 acc0 = {0.f, 0.f, 0.f, 0.f};
      f32x4 acc1 = {0.f, 0.f, 0.f, 0.f};
      acc0 = __builtin_amdgcn_mfma_f32_16x16x32_bf16(a[0][0], b0, acc0, 0, 0, 0);
      acc0 = __builtin_amdgcn_mfma_f32_16x16x32_bf16(a[0][1], b1, acc0, 0, 0, 0);
      acc1 = __builtin_amdgcn_mfma_f32_16x16x32_bf16(a[1][0], b0, acc1, 0, 0, 0);
      acc1 = __builtin_amdgcn_mfma_f32_16x16x32_bf16(a[1][1], b1, acc1, 0, 0, 0);

      float* dst = outn + (size_t)(p_base + prow) * MDIM + w_ * 32 + g * 4;
      *(f32x4*)(dst)      = acc0;   // m = 32w_ + 4g + {0..3}
      *(f32x4*)(dst + 16) = acc1;   // m = 32w_ + 16 + 4g + {0..3}
    }
  }
#undef PACKROW
}

extern "C" void kernel_launch(void* const* d_in, const int* in_sizes, int n_in,
                              void* d_out, int out_size, void* d_ws, size_t ws_size,
                              hipStream_t stream) {
  const float* x  = (const float*)d_in[0];   // (N, C, H, W) fp32
  const float* rm = (const float*)d_in[1];   // (N, C, M) fp32
  float* out = (float*)d_out;                // (N, P, M) fp32
  nlsa_kernel<<<dim3(NB * BLOCKS_PER_N), dim3(256), 0, stream>>>(x, rm, out);
}